// Round 5
// baseline (407.130 us; speedup 1.0000x reference)
//
#include <hip/hip_runtime.h>
#include <cstdint>
#include <cstddef>

#define B_ 2048
#define N_ 49
#define H_ 1024
#define A_ 512
#define M_ (B_*N_)   // 100352
#define NBB 5
#define NBLK ((B_ + NBB - 1)/NBB)   // 410 blocks, last has 3 batches

typedef __attribute__((ext_vector_type(8))) short short8;
typedef __attribute__((ext_vector_type(8))) unsigned short ushort8;
typedef __attribute__((ext_vector_type(4))) float f32x4;
typedef unsigned int u32;

__device__ inline unsigned short f2bf(float f){
  union { float f; unsigned u; } v; v.f = f;
  unsigned r = v.u + 0x7FFFu + ((v.u >> 16) & 1u);   // RNE
  return (unsigned short)(r >> 16);
}
__device__ inline float bf2f(unsigned short h){
  union { u32 u; float f; } v; v.u = ((u32)h) << 16; return v.f;
}
__device__ inline float fast_tanh(float x){
  float e = __expf(2.0f*x);
  return 1.0f - 2.0f/(e + 1.0f);
}
__device__ inline void gl16(const void* g, void* l){
  __builtin_amdgcn_global_load_lds((const __attribute__((address_space(1))) u32*)g,
                                   (__attribute__((address_space(3))) u32*)l, 16, 0, 0);
}

// ---------- W (H x A fp32, row-major) -> Wt (A x H bf16) ----------
__global__ __launch_bounds__(256) void k_transpose(
    const float* __restrict__ Wh, const float* __restrict__ Wimg,
    unsigned short* __restrict__ WtH, unsigned short* __restrict__ WtImg){
  const float* src = blockIdx.y ? Wimg : Wh;
  unsigned short* dst = blockIdx.y ? WtImg : WtH;
  int tk = (blockIdx.x & 31) * 32;
  int ta = (blockIdx.x >> 5) * 32;
  __shared__ unsigned short tile[32][33];
  int t = threadIdx.x;
  int r = t >> 3, c4 = t & 7;
  float4 vv = *(const float4*)(src + (size_t)(tk + r)*A_ + ta + c4*4);
  tile[c4*4+0][r] = f2bf(vv.x);
  tile[c4*4+1][r] = f2bf(vv.y);
  tile[c4*4+2][r] = f2bf(vv.z);
  tile[c4*4+3][r] = f2bf(vv.w);
  __syncthreads();
  ushort4 o;
  o.x = tile[r][c4*4+0]; o.y = tile[r][c4*4+1];
  o.z = tile[r][c4*4+2]; o.w = tile[r][c4*4+3];
  *(ushort4*)(dst + (size_t)(ta + r)*H_ + tk + c4*4) = o;
}

// ================= fallback GEMM core (round-1) =================
#define BK 64
#define LDK 72

__device__ inline void gemm_tile(const float* __restrict__ Asrc,
                                 const unsigned short* __restrict__ Wt,
                                 int m0, int a0, f32x4 acc[4][4],
                                 unsigned short (*sA)[LDK], unsigned short (*sB)[LDK]){
  const int t = threadIdx.x;
  const int l = t & 63, w = t >> 6;
  const int wr = w >> 1, wc = w & 1;
  const int g = l >> 4, c = l & 15;
  #pragma unroll
  for (int m=0;m<4;m++)
    #pragma unroll
    for (int n=0;n<4;n++)
      acc[m][n] = f32x4{0.f,0.f,0.f,0.f};

  for (int k0 = 0; k0 < H_; k0 += BK){
    #pragma unroll
    for (int i=0;i<8;i++){
      int f = i*256 + t;
      int row = f >> 4, c4 = f & 15;
      float4 vv = *(const float4*)(Asrc + (size_t)(m0+row)*H_ + k0 + c4*4);
      ushort4 h; h.x=f2bf(vv.x); h.y=f2bf(vv.y); h.z=f2bf(vv.z); h.w=f2bf(vv.w);
      *(ushort4*)&sA[row][c4*4] = h;
    }
    #pragma unroll
    for (int i=0;i<8;i++){
      int f = i*256 + t;
      int row = f >> 4, c4 = f & 15;
      *(ushort4*)&sB[row][c4*4] = *(const ushort4*)(Wt + (size_t)(a0+row)*H_ + k0 + c4*4);
    }
    __syncthreads();
    #pragma unroll
    for (int kk=0; kk<BK; kk+=32){
      short8 aF[4], bF[4];
      #pragma unroll
      for (int m=0;m<4;m++) aF[m] = *(const short8*)&sA[wr*64 + m*16 + c][kk + g*8];
      #pragma unroll
      for (int n=0;n<4;n++) bF[n] = *(const short8*)&sB[wc*64 + n*16 + c][kk + g*8];
      #pragma unroll
      for (int m=0;m<4;m++)
        #pragma unroll
        for (int n=0;n<4;n++)
          acc[m][n] = __builtin_amdgcn_mfma_f32_16x16x32_bf16(aF[m], bF[n], acc[m][n], 0, 0, 0);
    }
    __syncthreads();
  }
}

// ---------- h_proj = hidden @ W_h + b_h ----------
__global__ __launch_bounds__(256) void k_hproj(
    const float* __restrict__ hidden, const unsigned short* __restrict__ WtH,
    const float* __restrict__ b_h, float* __restrict__ hproj){
  __shared__ __align__(16) unsigned short sA[128][LDK];
  __shared__ __align__(16) unsigned short sB[128][LDK];
  f32x4 acc[4][4];
  int m0 = blockIdx.x * 128, a0 = blockIdx.y * 128;
  gemm_tile(hidden, WtH, m0, a0, acc, sA, sB);
  const int l = threadIdx.x & 63, w = threadIdx.x >> 6;
  const int wr = w >> 1, wc = w & 1, g = l >> 4, c = l & 15;
  #pragma unroll
  for (int n=0;n<4;n++){
    int col = a0 + wc*64 + n*16 + c;
    float bh = b_h[col];
    #pragma unroll
    for (int m=0;m<4;m++)
      #pragma unroll
      for (int r=0;r<4;r++){
        int rowg = m0 + wr*64 + m*16 + g*4 + r;
        hproj[(size_t)rowg*A_ + col] = acc[m][n][r] + bh;
      }
  }
}

// ============ fused: scores GEMM (a0-sweep in-block) + softmax + context ============
// Batch-aligned tiles: block bm owns batches [bm*5, bm*5+NB), rows m0..m0+NB*49.
// Sweep 0: A staged fp32->bf16 in regs (writes bf16 copy to imgb); sweep 1: A via
// global_load_lds from imgb. B (Wt) via global_load_lds both sweeps. 2-barrier
// K-loop with counted vmcnt (round-4 proven). XOR swizzle byte^=((row&7)<<4).
__global__ __launch_bounds__(512, 2) void k_fused(
    const float* __restrict__ img, unsigned short* __restrict__ imgb,
    const unsigned short* __restrict__ Wt, const float* __restrict__ hproj,
    const float* __restrict__ b_img, const float* __restrict__ cov,
    const float* __restrict__ Wcov, const float* __restrict__ v,
    float* __restrict__ outCtx, float* __restrict__ outAlpha){
  __shared__ __align__(16) char lds[131072];
  __shared__ float sS[256];
  __shared__ float sH[NBB][256];
  __shared__ float sAl[256];

  const int t = threadIdx.x;
  const int l = t & 63, w = t >> 6;       // 8 waves
  const int wr = w >> 2, wc = w & 3;      // 2 (M) x 4 (N)
  const int g = l >> 4, c = l & 15;
  const int cm = (c & 7) << 4;            // read-side XOR swizzle

  const int bm = blockIdx.x;
  const int bb0 = bm * NBB;
  const int NB = min(NBB, B_ - bb0);
  const int mrows = NB * N_;              // 245 or 147
  const int m0 = bb0 * N_;

  if (t < 256) sS[t] = 0.f;

  // staging geometry
  const int rsub = l >> 3;
  const int ksw  = ((l & 7) ^ rsub) * 8;  // gl16 pre-swizzled k-offset (elements)
  const int arow = t >> 1, akq = t & 1;   // fp32 A staging: row, k-half (32 floats)
  const int arC  = (arow < mrows) ? arow : 0;   // clamp pad rows into own panel

  f32x4 acc[8][4];

  auto stageB = [&](int bn, int k0, int a0){
    #pragma unroll
    for (int h=0;h<2;h++)
      #pragma unroll
      for (int q=0;q<2;q++){
        int row = h*128 + w*16 + q*8 + rsub;
        gl16(Wt + (size_t)(a0 + row)*H_ + k0 + ksw,
             lds + bn*65536 + 32768 + h*16384 + w*2048 + q*1024);
      }
  };
  auto stageA2 = [&](int bn, int k0){     // sweep 1: bf16 copy via gl16
    #pragma unroll
    for (int h=0;h<2;h++)
      #pragma unroll
      for (int q=0;q<2;q++){
        int row = h*128 + w*16 + q*8 + rsub;
        int rr = (row < mrows) ? row : 0;
        gl16(imgb + (size_t)(m0 + rr)*H_ + k0 + ksw,
             lds + bn*65536 + h*16384 + w*2048 + q*1024);
      }
  };

  auto compute = [&](int tt){
    const int cur = (tt & 1) << 16;
    const int abase = cur + wr*16384;
    const int bbase = cur + 32768 + (wc>>1)*16384;
    const int brow  = (wc & 1)*64;
    #pragma unroll
    for (int kb2=0; kb2<2; ++kb2){
      const int ko = kb2*64;              // k byte base
      short8 bF[4];
      #pragma unroll
      for (int n=0;n<4;n++)
        bF[n] = *(const short8*)(lds + bbase + (brow + n*16 + c)*128 + ((ko + g*16) ^ cm));
      #pragma unroll
      for (int mh=0; mh<2; ++mh){
        short8 aF[4];
        #pragma unroll
        for (int i=0;i<4;i++)
          aF[i] = *(const short8*)(lds + abase + ((mh*4+i)*16 + c)*128 + ((ko + g*16) ^ cm));
        __builtin_amdgcn_s_setprio(1);
        #pragma unroll
        for (int i=0;i<4;i++)
          #pragma unroll
          for (int n=0;n<4;n++)
            acc[mh*4+i][n] = __builtin_amdgcn_mfma_f32_16x16x32_bf16(aF[i], bF[n], acc[mh*4+i][n], 0, 0, 0);
        __builtin_amdgcn_s_setprio(0);
      }
    }
  };

  auto epilogue = [&](int a0){
    for (int idx = t; idx < NB*256; idx += 512){
      int bb = idx >> 8, a = idx & 255;
      sH[bb][a] = hproj[(size_t)(bb0 + bb)*A_ + a0 + a];
    }
    asm volatile("s_waitcnt lgkmcnt(0)" ::: "memory");
    asm volatile("s_barrier" ::: "memory");
    float vv[4], bi[4], wcv[4];
    #pragma unroll
    for (int n=0;n<4;n++){
      int colg = a0 + wc*64 + n*16 + c;
      vv[n] = v[colg]; bi[n] = b_img[colg]; wcv[n] = Wcov[colg];
    }
    #pragma unroll
    for (int m=0;m<8;m++){
      #pragma unroll
      for (int r=0;r<4;r++){
        int rowl = wr*128 + m*16 + g*4 + r;
        if (rowl < mrows){               // uniform within 16-lane shfl group
          int bb = rowl / N_;
          float cv = cov[m0 + rowl];
          float s = 0.f;
          #pragma unroll
          for (int n=0;n<4;n++){
            float x = acc[m][n][r] + sH[bb][wc*64 + n*16 + c] + bi[n] + cv*wcv[n];
            s += fast_tanh(x) * vv[n];
          }
          s += __shfl_xor(s, 1, 16);
          s += __shfl_xor(s, 2, 16);
          s += __shfl_xor(s, 4, 16);
          s += __shfl_xor(s, 8, 16);
          if (c == 0) atomicAdd(&sS[rowl], s);
        }
      }
    }
    asm volatile("s_waitcnt lgkmcnt(0)" ::: "memory");
    asm volatile("s_barrier" ::: "memory");
  };

  // ---------------- sweep 0: a0=0, fp32 A + bf16-copy write ----------------
  {
    #pragma unroll
    for (int m=0;m<8;m++)
      #pragma unroll
      for (int n=0;n<4;n++)
        acc[m][n] = f32x4{0.f,0.f,0.f,0.f};

    float4 av[8];
    auto loadA = [&](int k0){
      const float4* asrc = (const float4*)(img + (size_t)(m0 + arC)*H_ + k0 + akq*32);
      #pragma unroll
      for (int i=0;i<8;i++) av[i] = asrc[i];
    };
    auto writeA = [&](int bn, int k0){
      #pragma unroll
      for (int j=0;j<4;j++){
        ushort8 o;
        o[0]=f2bf(av[2*j].x); o[1]=f2bf(av[2*j].y); o[2]=f2bf(av[2*j].z); o[3]=f2bf(av[2*j].w);
        o[4]=f2bf(av[2*j+1].x); o[5]=f2bf(av[2*j+1].y); o[6]=f2bf(av[2*j+1].z); o[7]=f2bf(av[2*j+1].w);
        int ch = akq*4 + j;
        *(ushort8*)(lds + bn*65536 + arow*128 + ((ch*16) ^ ((arow&7)<<4))) = o;
        if (arow < mrows)
          *(ushort8*)(imgb + (size_t)(m0 + arow)*H_ + k0 + ch*8) = o;
      }
    };

    loadA(0);
    stageB(0, 0, 0);
    asm volatile("s_waitcnt vmcnt(4)" ::: "memory");   // av ready (leaves B(0))
    writeA(0, 0);
    for (int tt=0; tt<16; ++tt){
      if (tt < 15){
        loadA((tt+1)*64);
        stageB((tt+1)&1, (tt+1)*64, 0);
        asm volatile("s_waitcnt vmcnt(4)" ::: "memory"); // av(t+1) ready, B(t)+stores drained
        writeA((tt+1)&1, (tt+1)*64);
      } else {
        asm volatile("s_waitcnt vmcnt(0)" ::: "memory");
      }
      asm volatile("s_waitcnt lgkmcnt(0)" ::: "memory"); // ds_writes visible
      asm volatile("s_barrier" ::: "memory");
      compute(tt);
      asm volatile("s_barrier" ::: "memory");
    }
    epilogue(0);
  }

  // ---------------- sweep 1: a0=256, bf16 A via gl16 ----------------
  {
    #pragma unroll
    for (int m=0;m<8;m++)
      #pragma unroll
      for (int n=0;n<4;n++)
        acc[m][n] = f32x4{0.f,0.f,0.f,0.f};

    stageA2(0, 0);
    stageB(0, 0, 256);
    for (int tt=0; tt<16; ++tt){
      if (tt < 15){
        stageA2((tt+1)&1, (tt+1)*64);
        stageB((tt+1)&1, (tt+1)*64, 256);
        asm volatile("s_waitcnt vmcnt(8)" ::: "memory"); // tile-tt's 8 landed
      } else {
        asm volatile("s_waitcnt vmcnt(0)" ::: "memory");
      }
      asm volatile("s_barrier" ::: "memory");
      compute(tt);
      asm volatile("s_barrier" ::: "memory");
    }
    epilogue(256);
  }

  // ---------------- softmax (one wave per batch) + context ----------------
  asm volatile("s_barrier" ::: "memory");
  if (w < NB){
    int b = w;
    float s = (l < N_) ? sS[b*N_ + l] : -1e30f;
    float mx = s;
    #pragma unroll
    for (int off=32; off>=1; off>>=1) mx = fmaxf(mx, __shfl_xor(mx, off));
    float e = (l < N_) ? __expf(s - mx) : 0.f;
    float sum = e;
    #pragma unroll
    for (int off=32; off>=1; off>>=1) sum += __shfl_xor(sum, off);
    float al = e / sum;
    if (l < N_){
      sAl[b*N_ + l] = al;
      outAlpha[(size_t)(m0 + b*N_ + l)] = al;
    }
  }
  asm volatile("s_waitcnt lgkmcnt(0)" ::: "memory");
  asm volatile("s_barrier" ::: "memory");

  const ushort2* ib2 = (const ushort2*)imgb;
  for (int b=0; b<NB; ++b){
    float ax = 0.f, ay = 0.f;
    #pragma unroll 7
    for (int n=0; n<N_; ++n){
      float al = sAl[b*N_ + n];
      ushort2 u = ib2[(size_t)(m0 + b*N_ + n)*(H_/2) + t];
      ax += al * bf2f(u.x);
      ay += al * bf2f(u.y);
    }
    float2 o; o.x = ax; o.y = ay;
    *(float2*)(outCtx + (size_t)(bb0 + b)*H_ + t*2) = o;
  }
}

// ---------- fallback score GEMM (round-1) ----------
__global__ __launch_bounds__(256) void k_scores_f(
    const float* __restrict__ img, const unsigned short* __restrict__ WtImg,
    const float* __restrict__ hproj, const float* __restrict__ b_img,
    const float* __restrict__ cov, const float* __restrict__ Wcov,
    const float* __restrict__ v, float* __restrict__ scores){
  __shared__ __align__(16) unsigned short sA[128][LDK];
  __shared__ __align__(16) unsigned short sB[128][LDK];
  __shared__ float sH[4][128];
  f32x4 acc[4][4];
  int m0 = blockIdx.x * 128, a0 = blockIdx.y * 128;
  gemm_tile(img, WtImg, m0, a0, acc, sA, sB);
  int bFirst = m0 / N_;
  int bLast  = (m0 + 127) / N_;
  int nB = bLast - bFirst + 1;
  for (int idx = threadIdx.x; idx < nB*128; idx += 256){
    int bb = idx >> 7, a = idx & 127;
    sH[bb][a] = hproj[(size_t)(bFirst + bb)*A_ + a0 + a];
  }
  __syncthreads();
  const int l = threadIdx.x & 63, w = threadIdx.x >> 6;
  const int wr = w >> 1, wc = w & 1, g = l >> 4, c = l & 15;
  float vv[4], bi[4], wcv[4];
  #pragma unroll
  for (int n=0;n<4;n++){
    int col = a0 + wc*64 + n*16 + c;
    vv[n] = v[col]; bi[n] = b_img[col]; wcv[n] = Wcov[col];
  }
  #pragma unroll
  for (int m=0;m<4;m++)
    #pragma unroll
    for (int r=0;r<4;r++){
      int rowg = m0 + wr*64 + m*16 + g*4 + r;
      int bb = rowg / N_;
      float cv = cov[rowg];
      float s = 0.f;
      #pragma unroll
      for (int n=0;n<4;n++){
        float x = acc[m][n][r] + sH[bb - bFirst][wc*64 + n*16 + c] + bi[n] + cv*wcv[n];
        s += fast_tanh(x) * vv[n];
      }
      s += __shfl_xor(s, 1, 16);
      s += __shfl_xor(s, 2, 16);
      s += __shfl_xor(s, 4, 16);
      s += __shfl_xor(s, 8, 16);
      if (c == 0) atomicAdd(&scores[rowg], s);
    }
}

// ---------- fallback softmax + context ----------
__global__ __launch_bounds__(256) void k_ctx_f(
    const float* __restrict__ img, const float* __restrict__ scores,
    float* __restrict__ outCtx, float* __restrict__ outAlpha){
  int b = blockIdx.x;
  __shared__ float sAl[N_];
  int t = threadIdx.x;
  if (t < 64){
    float s = (t < N_) ? scores[(size_t)b*N_ + t] : -1e30f;
    float m = s;
    #pragma unroll
    for (int off=32; off>=1; off>>=1) m = fmaxf(m, __shfl_xor(m, off));
    float e = (t < N_) ? __expf(s - m) : 0.f;
    float sum = e;
    #pragma unroll
    for (int off=32; off>=1; off>>=1) sum += __shfl_xor(sum, off);
    float al = e / sum;
    if (t < N_){ sAl[t] = al; outAlpha[(size_t)b*N_ + t] = al; }
  }
  __syncthreads();
  const float4* ib = (const float4*)(img + (size_t)b*N_*H_);
  float4 acc = {0.f,0.f,0.f,0.f};
  for (int n=0;n<N_;n++){
    float al = sAl[n];
    float4 x = ib[n*(H_/4) + t];
    acc.x += al*x.x; acc.y += al*x.y; acc.z += al*x.z; acc.w += al*x.w;
  }
  *(float4*)(outCtx + (size_t)b*H_ + t*4) = acc;
}

extern "C" void kernel_launch(void* const* d_in, const int* in_sizes, int n_in,
                              void* d_out, int out_size, void* d_ws, size_t ws_size,
                              hipStream_t stream){
  const float* hidden = (const float*)d_in[0];
  const float* img    = (const float*)d_in[1];
  const float* cov    = (const float*)d_in[2];
  const float* W_h    = (const float*)d_in[3];
  const float* b_h    = (const float*)d_in[4];
  const float* W_img  = (const float*)d_in[5];
  const float* b_img  = (const float*)d_in[6];
  const float* W_cov  = (const float*)d_in[7];
  const float* v      = (const float*)d_in[8];

  char* ws = (char*)d_ws;
  unsigned short* WtH   = (unsigned short*)ws;               // 1 MB
  unsigned short* WtImg = (unsigned short*)(ws + (1u<<20));  // 1 MB
  float* hproj   = (float*)(ws + (2u<<20));                  // 4 MB
  float* scoresF = (float*)(ws + (6u<<20));                  // fallback scores
  unsigned short* imgb = (unsigned short*)(ws + (8u<<20));   // 196 MB bf16 copy

  float* outCtx   = (float*)d_out;
  float* outAlpha = outCtx + (size_t)B_*H_;

  const size_t needed = (8ull<<20) + (size_t)M_*H_*2;

  k_transpose<<<dim3(512, 2), 256, 0, stream>>>(W_h, W_img, WtH, WtImg);
  k_hproj<<<dim3(B_/128, A_/128), 256, 0, stream>>>(hidden, WtH, b_h, hproj);

  if (ws_size >= needed){
    k_fused<<<NBLK, 512, 0, stream>>>(img, imgb, WtImg, hproj, b_img, cov, W_cov, v,
                                      outCtx, outAlpha);
  } else {
    hipMemsetAsync(scoresF, 0, (size_t)M_*sizeof(float), stream);
    k_scores_f<<<dim3(M_/128, A_/128), 256, 0, stream>>>(img, WtImg, hproj, b_img, cov, W_cov, v, scoresF);
    k_ctx_f<<<B_, 256, 0, stream>>>(img, scoresF, outCtx, outAlpha);
  }
}

// Round 6
// 383.857 us; speedup vs baseline: 1.0606x; 1.0606x over previous
//
#include <hip/hip_runtime.h>
#include <cstdint>
#include <cstddef>

#define B_ 2048
#define N_ 49
#define H_ 1024
#define A_ 512
#define M_ (B_*N_)   // 100352
#define NBB 5
#define NBLK ((B_ + NBB - 1)/NBB)   // 410 blocks, last has 3 batches

typedef __attribute__((ext_vector_type(8))) short short8;
typedef __attribute__((ext_vector_type(8))) unsigned short ushort8;
typedef __attribute__((ext_vector_type(4))) float f32x4;
typedef unsigned int u32;

__device__ inline unsigned short f2bf(float f){
  union { float f; unsigned u; } v; v.f = f;
  unsigned r = v.u + 0x7FFFu + ((v.u >> 16) & 1u);   // RNE
  return (unsigned short)(r >> 16);
}
__device__ inline float bf2f(unsigned short h){
  union { u32 u; float f; } v; v.u = ((u32)h) << 16; return v.f;
}
__device__ inline float fast_tanh(float x){
  float e = __expf(2.0f*x);
  return 1.0f - 2.0f/(e + 1.0f);
}
__device__ inline void gl16(const void* g, void* l){
  __builtin_amdgcn_global_load_lds((const __attribute__((address_space(1))) u32*)g,
                                   (__attribute__((address_space(3))) u32*)l, 16, 0, 0);
}

// ---------- W (H x A fp32, row-major) -> Wt (A x H bf16) ----------
__global__ __launch_bounds__(256) void k_transpose(
    const float* __restrict__ Wh, const float* __restrict__ Wimg,
    unsigned short* __restrict__ WtH, unsigned short* __restrict__ WtImg){
  const float* src = blockIdx.y ? Wimg : Wh;
  unsigned short* dst = blockIdx.y ? WtImg : WtH;
  int tk = (blockIdx.x & 31) * 32;
  int ta = (blockIdx.x >> 5) * 32;
  __shared__ unsigned short tile[32][33];
  int t = threadIdx.x;
  int r = t >> 3, c4 = t & 7;
  float4 vv = *(const float4*)(src + (size_t)(tk + r)*A_ + ta + c4*4);
  tile[c4*4+0][r] = f2bf(vv.x);
  tile[c4*4+1][r] = f2bf(vv.y);
  tile[c4*4+2][r] = f2bf(vv.z);
  tile[c4*4+3][r] = f2bf(vv.w);
  __syncthreads();
  ushort4 o;
  o.x = tile[r][c4*4+0]; o.y = tile[r][c4*4+1];
  o.z = tile[r][c4*4+2]; o.w = tile[r][c4*4+3];
  *(ushort4*)(dst + (size_t)(ta + r)*H_ + tk + c4*4) = o;
}

// ================= fallback GEMM core (round-1) =================
#define BK 64
#define LDK 72

__device__ inline void gemm_tile(const float* __restrict__ Asrc,
                                 const unsigned short* __restrict__ Wt,
                                 int m0, int a0, f32x4 acc[4][4],
                                 unsigned short (*sA)[LDK], unsigned short (*sB)[LDK]){
  const int t = threadIdx.x;
  const int l = t & 63, w = t >> 6;
  const int wr = w >> 1, wc = w & 1;
  const int g = l >> 4, c = l & 15;
  #pragma unroll
  for (int m=0;m<4;m++)
    #pragma unroll
    for (int n=0;n<4;n++)
      acc[m][n] = f32x4{0.f,0.f,0.f,0.f};

  for (int k0 = 0; k0 < H_; k0 += BK){
    #pragma unroll
    for (int i=0;i<8;i++){
      int f = i*256 + t;
      int row = f >> 4, c4 = f & 15;
      float4 vv = *(const float4*)(Asrc + (size_t)(m0+row)*H_ + k0 + c4*4);
      ushort4 h; h.x=f2bf(vv.x); h.y=f2bf(vv.y); h.z=f2bf(vv.z); h.w=f2bf(vv.w);
      *(ushort4*)&sA[row][c4*4] = h;
    }
    #pragma unroll
    for (int i=0;i<8;i++){
      int f = i*256 + t;
      int row = f >> 4, c4 = f & 15;
      *(ushort4*)&sB[row][c4*4] = *(const ushort4*)(Wt + (size_t)(a0+row)*H_ + k0 + c4*4);
    }
    __syncthreads();
    #pragma unroll
    for (int kk=0; kk<BK; kk+=32){
      short8 aF[4], bF[4];
      #pragma unroll
      for (int m=0;m<4;m++) aF[m] = *(const short8*)&sA[wr*64 + m*16 + c][kk + g*8];
      #pragma unroll
      for (int n=0;n<4;n++) bF[n] = *(const short8*)&sB[wc*64 + n*16 + c][kk + g*8];
      #pragma unroll
      for (int m=0;m<4;m++)
        #pragma unroll
        for (int n=0;n<4;n++)
          acc[m][n] = __builtin_amdgcn_mfma_f32_16x16x32_bf16(aF[m], bF[n], acc[m][n], 0, 0, 0);
    }
    __syncthreads();
  }
}

// ---------- h_proj = hidden @ W_h + b_h ----------
__global__ __launch_bounds__(256) void k_hproj(
    const float* __restrict__ hidden, const unsigned short* __restrict__ WtH,
    const float* __restrict__ b_h, float* __restrict__ hproj){
  __shared__ __align__(16) unsigned short sA[128][LDK];
  __shared__ __align__(16) unsigned short sB[128][LDK];
  f32x4 acc[4][4];
  int m0 = blockIdx.x * 128, a0 = blockIdx.y * 128;
  gemm_tile(hidden, WtH, m0, a0, acc, sA, sB);
  const int l = threadIdx.x & 63, w = threadIdx.x >> 6;
  const int wr = w >> 1, wc = w & 1, g = l >> 4, c = l & 15;
  #pragma unroll
  for (int n=0;n<4;n++){
    int col = a0 + wc*64 + n*16 + c;
    float bh = b_h[col];
    #pragma unroll
    for (int m=0;m<4;m++)
      #pragma unroll
      for (int r=0;r<4;r++){
        int rowg = m0 + wr*64 + m*16 + g*4 + r;
        hproj[(size_t)rowg*A_ + col] = acc[m][n][r] + bh;
      }
  }
}

// ============ fused: scores GEMM (a0-sweep in-block) + softmax + context ============
// Sweep 0: A reg-staged fp32->bf16 with issue-early/write-late (T14): loads for
// tile t+1 issued BEFORE compute(t), converted+written to LDS AFTER compute(t).
// Also writes block-private bf16 copy to imgb. Sweep 1: A via gl16 from imgb.
// 2-barrier K-loop, counted vmcnt, XOR swizzle byte^=((row&7)<<4).
__global__ __launch_bounds__(512, 2) void k_fused(
    const float* __restrict__ img, unsigned short* __restrict__ imgb,
    const unsigned short* __restrict__ Wt, const float* __restrict__ hproj,
    const float* __restrict__ b_img, const float* __restrict__ cov,
    const float* __restrict__ Wcov, const float* __restrict__ v,
    float* __restrict__ outCtx, float* __restrict__ outAlpha){
  __shared__ __align__(16) char lds[131072];
  __shared__ float sS[256];
  __shared__ float sH[NBB][256];
  __shared__ float sAl[256];

  const int t = threadIdx.x;
  const int l = t & 63, w = t >> 6;       // 8 waves
  const int wr = w >> 2, wc = w & 3;      // 2 (M) x 4 (N)
  const int g = l >> 4, c = l & 15;
  const int cm = (c & 7) << 4;            // read-side XOR swizzle

  const int bm = blockIdx.x;
  const int bb0 = bm * NBB;
  const int NB = min(NBB, B_ - bb0);
  const int mrows = NB * N_;              // 245 or 147
  const int m0 = bb0 * N_;

  if (t < 256) sS[t] = 0.f;

  // staging geometry
  const int rsub = l >> 3;
  const int ksw  = ((l & 7) ^ rsub) * 8;  // gl16 pre-swizzled k-offset (elements)
  const int arow = t >> 1, akq = t & 1;   // fp32 A staging: row, k-half (32 floats)
  const int arC  = (arow < mrows) ? arow : 0;   // clamp pad rows

  f32x4 acc[8][4];

  auto stageB = [&](int bn, int k0, int a0){
    #pragma unroll
    for (int h=0;h<2;h++)
      #pragma unroll
      for (int q=0;q<2;q++){
        int row = h*128 + w*16 + q*8 + rsub;
        gl16(Wt + (size_t)(a0 + row)*H_ + k0 + ksw,
             lds + bn*65536 + 32768 + h*16384 + w*2048 + q*1024);
      }
  };
  auto stageA2 = [&](int bn, int k0){     // sweep 1: bf16 copy via gl16
    #pragma unroll
    for (int h=0;h<2;h++)
      #pragma unroll
      for (int q=0;q<2;q++){
        int row = h*128 + w*16 + q*8 + rsub;
        int rr = (row < mrows) ? row : 0;
        gl16(imgb + (size_t)(m0 + rr)*H_ + k0 + ksw,
             lds + bn*65536 + h*16384 + w*2048 + q*1024);
      }
  };

  auto compute = [&](int tt){
    const int cur = (tt & 1) << 16;
    const int abase = cur + wr*16384;
    const int bbase = cur + 32768 + (wc>>1)*16384;
    const int brow  = (wc & 1)*64;
    #pragma unroll
    for (int kb2=0; kb2<2; ++kb2){
      const int ko = kb2*64;              // k byte base
      short8 bF[4];
      #pragma unroll
      for (int n=0;n<4;n++)
        bF[n] = *(const short8*)(lds + bbase + (brow + n*16 + c)*128 + ((ko + g*16) ^ cm));
      #pragma unroll
      for (int mh=0; mh<2; ++mh){
        short8 aF[4];
        #pragma unroll
        for (int i=0;i<4;i++)
          aF[i] = *(const short8*)(lds + abase + ((mh*4+i)*16 + c)*128 + ((ko + g*16) ^ cm));
        __builtin_amdgcn_s_setprio(1);
        #pragma unroll
        for (int i=0;i<4;i++)
          #pragma unroll
          for (int n=0;n<4;n++)
            acc[mh*4+i][n] = __builtin_amdgcn_mfma_f32_16x16x32_bf16(aF[i], bF[n], acc[mh*4+i][n], 0, 0, 0);
        __builtin_amdgcn_s_setprio(0);
      }
    }
  };

  auto epilogue = [&](int a0){
    for (int idx = t; idx < NB*256; idx += 512){
      int bb = idx >> 8, a = idx & 255;
      sH[bb][a] = hproj[(size_t)(bb0 + bb)*A_ + a0 + a];
    }
    asm volatile("s_waitcnt lgkmcnt(0)" ::: "memory");
    asm volatile("s_barrier" ::: "memory");
    float vv[4], bi[4], wcv[4];
    #pragma unroll
    for (int n=0;n<4;n++){
      int colg = a0 + wc*64 + n*16 + c;
      vv[n] = v[colg]; bi[n] = b_img[colg]; wcv[n] = Wcov[colg];
    }
    #pragma unroll
    for (int m=0;m<8;m++){
      #pragma unroll
      for (int r=0;r<4;r++){
        int rowl = wr*128 + m*16 + g*4 + r;
        if (rowl < mrows){               // uniform within 16-lane shfl group
          int bb = rowl / N_;
          float cv = cov[m0 + rowl];
          float s = 0.f;
          #pragma unroll
          for (int n=0;n<4;n++){
            float x = acc[m][n][r] + sH[bb][wc*64 + n*16 + c] + bi[n] + cv*wcv[n];
            s += fast_tanh(x) * vv[n];
          }
          s += __shfl_xor(s, 1, 16);
          s += __shfl_xor(s, 2, 16);
          s += __shfl_xor(s, 4, 16);
          s += __shfl_xor(s, 8, 16);
          if (c == 0) atomicAdd(&sS[rowl], s);
        }
      }
    }
    asm volatile("s_waitcnt lgkmcnt(0)" ::: "memory");
    asm volatile("s_barrier" ::: "memory");
  };

  // ---------------- sweep 0: a0=0, fp32 A reg-staged, issue-early/write-late ----------------
  {
    #pragma unroll
    for (int m=0;m<8;m++)
      #pragma unroll
      for (int n=0;n<4;n++)
        acc[m][n] = f32x4{0.f,0.f,0.f,0.f};

    float4 av[8];
    auto loadA = [&](int k0){
      const float4* asrc = (const float4*)(img + (size_t)(m0 + arC)*H_ + k0 + akq*32);
      #pragma unroll
      for (int i=0;i<8;i++) av[i] = asrc[i];
    };
    auto writeA = [&](int bn, int k0){
      #pragma unroll
      for (int j=0;j<4;j++){
        ushort8 o;
        o[0]=f2bf(av[2*j].x); o[1]=f2bf(av[2*j].y); o[2]=f2bf(av[2*j].z); o[3]=f2bf(av[2*j].w);
        o[4]=f2bf(av[2*j+1].x); o[5]=f2bf(av[2*j+1].y); o[6]=f2bf(av[2*j+1].z); o[7]=f2bf(av[2*j+1].w);
        int ch = akq*4 + j;
        *(ushort8*)(lds + bn*65536 + arow*128 + ((ch*16) ^ ((arow&7)<<4))) = o;
        if (arow < mrows)
          *(ushort8*)(imgb + (size_t)(m0 + arow)*H_ + k0 + ch*8) = o;
      }
    };

    // prologue: tile 0 staged synchronously
    loadA(0);
    stageB(0, 0, 0);
    asm volatile("s_waitcnt vmcnt(4)" ::: "memory");   // av(0) ready (B gl16 pending)
    writeA(0, 0);
    asm volatile("s_waitcnt lgkmcnt(0)" ::: "memory");
    asm volatile("s_waitcnt vmcnt(4)" ::: "memory");   // B(0) landed (stores pending)
    asm volatile("s_barrier" ::: "memory");

    for (int tt=0; tt<16; ++tt){
      const int nxt = (tt+1) & 1;
      if (tt < 15){
        loadA((tt+1)*64);                               // 8 loads -> regs (prefetch)
        stageB(nxt, (tt+1)*64, 0);                      // 4 gl16 -> buf[nxt]
        asm volatile("" ::: "memory");                  // pin loads above compute
      }
      compute(tt);                                      // buf[cur]; hides A latency
      if (tt < 15){
        asm volatile("s_waitcnt vmcnt(4)" ::: "memory"); // stores(tt)+loadA(tt+1) retired
        writeA(nxt, (tt+1)*64);                         // ds_write buf[nxt] + stores
        asm volatile("s_waitcnt lgkmcnt(0)" ::: "memory"); // ds_writes visible
        asm volatile("s_waitcnt vmcnt(4)" ::: "memory"); // gl16(tt+1) landed
      } else {
        asm volatile("s_waitcnt vmcnt(0)" ::: "memory"); // drain stores for sweep 1
      }
      asm volatile("s_barrier" ::: "memory");
    }
    epilogue(0);
  }

  // ---------------- sweep 1: a0=256, bf16 A via gl16 (round-4 proven) ----------------
  {
    #pragma unroll
    for (int m=0;m<8;m++)
      #pragma unroll
      for (int n=0;n<4;n++)
        acc[m][n] = f32x4{0.f,0.f,0.f,0.f};

    stageA2(0, 0);
    stageB(0, 0, 256);
    for (int tt=0; tt<16; ++tt){
      if (tt < 15){
        stageA2((tt+1)&1, (tt+1)*64);
        stageB((tt+1)&1, (tt+1)*64, 256);
        asm volatile("s_waitcnt vmcnt(8)" ::: "memory"); // tile-tt's 8 landed
      } else {
        asm volatile("s_waitcnt vmcnt(0)" ::: "memory");
      }
      asm volatile("s_barrier" ::: "memory");
      compute(tt);
      asm volatile("s_barrier" ::: "memory");
    }
    epilogue(256);
  }

  // ---------------- softmax (one wave per batch) + context ----------------
  asm volatile("s_barrier" ::: "memory");
  if (w < NB){
    int b = w;
    float s = (l < N_) ? sS[b*N_ + l] : -1e30f;
    float mx = s;
    #pragma unroll
    for (int off=32; off>=1; off>>=1) mx = fmaxf(mx, __shfl_xor(mx, off));
    float e = (l < N_) ? __expf(s - mx) : 0.f;
    float sum = e;
    #pragma unroll
    for (int off=32; off>=1; off>>=1) sum += __shfl_xor(sum, off);
    float al = e / sum;
    if (l < N_){
      sAl[b*N_ + l] = al;
      outAlpha[(size_t)(m0 + b*N_ + l)] = al;
    }
  }
  asm volatile("s_waitcnt lgkmcnt(0)" ::: "memory");
  asm volatile("s_barrier" ::: "memory");

  // context: 8 B/lane bf16 reads; batches split across thread halves
  const int th = t >> 8;        // 0 or 1
  const int tc = t & 255;       // ushort4 column
  for (int b = th; b < NB; b += 2){
    float ax=0.f, ay=0.f, az=0.f, aw=0.f;
    #pragma unroll 7
    for (int n=0; n<N_; ++n){
      float al = sAl[b*N_ + n];
      ushort4 u = *(const ushort4*)(imgb + (size_t)(m0 + b*N_ + n)*H_ + tc*4);
      ax += al*bf2f(u.x); ay += al*bf2f(u.y);
      az += al*bf2f(u.z); aw += al*bf2f(u.w);
    }
    float4 o; o.x=ax; o.y=ay; o.z=az; o.w=aw;
    *(float4*)(outCtx + (size_t)(bb0 + b)*H_ + tc*4) = o;
  }
}

// ---------- fallback score GEMM (round-1) ----------
__global__ __launch_bounds__(256) void k_scores_f(
    const float* __restrict__ img, const unsigned short* __restrict__ WtImg,
    const float* __restrict__ hproj, const float* __restrict__ b_img,
    const float* __restrict__ cov, const float* __restrict__ Wcov,
    const float* __restrict__ v, float* __restrict__ scores){
  __shared__ __align__(16) unsigned short sA[128][LDK];
  __shared__ __align__(16) unsigned short sB[128][LDK];
  __shared__ float sH[4][128];
  f32x4 acc[4][4];
  int m0 = blockIdx.x * 128, a0 = blockIdx.y * 128;
  gemm_tile(img, WtImg, m0, a0, acc, sA, sB);
  int bFirst = m0 / N_;
  int bLast  = (m0 + 127) / N_;
  int nB = bLast - bFirst + 1;
  for (int idx = threadIdx.x; idx < nB*128; idx += 256){
    int bb = idx >> 7, a = idx & 127;
    sH[bb][a] = hproj[(size_t)(bFirst + bb)*A_ + a0 + a];
  }
  __syncthreads();
  const int l = threadIdx.x & 63, w = threadIdx.x >> 6;
  const int wr = w >> 1, wc = w & 1, g = l >> 4, c = l & 15;
  float vv[4], bi[4], wcv[4];
  #pragma unroll
  for (int n=0;n<4;n++){
    int col = a0 + wc*64 + n*16 + c;
    vv[n] = v[col]; bi[n] = b_img[col]; wcv[n] = Wcov[col];
  }
  #pragma unroll
  for (int m=0;m<4;m++)
    #pragma unroll
    for (int r=0;r<4;r++){
      int rowg = m0 + wr*64 + m*16 + g*4 + r;
      int bb = rowg / N_;
      float cv = cov[rowg];
      float s = 0.f;
      #pragma unroll
      for (int n=0;n<4;n++){
        float x = acc[m][n][r] + sH[bb - bFirst][wc*64 + n*16 + c] + bi[n] + cv*wcv[n];
        s += fast_tanh(x) * vv[n];
      }
      s += __shfl_xor(s, 1, 16);
      s += __shfl_xor(s, 2, 16);
      s += __shfl_xor(s, 4, 16);
      s += __shfl_xor(s, 8, 16);
      if (c == 0) atomicAdd(&scores[rowg], s);
    }
}

// ---------- fallback softmax + context ----------
__global__ __launch_bounds__(256) void k_ctx_f(
    const float* __restrict__ img, const float* __restrict__ scores,
    float* __restrict__ outCtx, float* __restrict__ outAlpha){
  int b = blockIdx.x;
  __shared__ float sAl[N_];
  int t = threadIdx.x;
  if (t < 64){
    float s = (t < N_) ? scores[(size_t)b*N_ + t] : -1e30f;
    float m = s;
    #pragma unroll
    for (int off=32; off>=1; off>>=1) m = fmaxf(m, __shfl_xor(m, off));
    float e = (t < N_) ? __expf(s - m) : 0.f;
    float sum = e;
    #pragma unroll
    for (int off=32; off>=1; off>>=1) sum += __shfl_xor(sum, off);
    float al = e / sum;
    if (t < N_){ sAl[t] = al; outAlpha[(size_t)b*N_ + t] = al; }
  }
  __syncthreads();
  const float4* ib = (const float4*)(img + (size_t)b*N_*H_);
  float4 acc = {0.f,0.f,0.f,0.f};
  for (int n=0;n<N_;n++){
    float al = sAl[n];
    float4 x = ib[n*(H_/4) + t];
    acc.x += al*x.x; acc.y += al*x.y; acc.z += al*x.z; acc.w += al*x.w;
  }
  *(float4*)(outCtx + (size_t)b*H_ + t*4) = acc;
}

extern "C" void kernel_launch(void* const* d_in, const int* in_sizes, int n_in,
                              void* d_out, int out_size, void* d_ws, size_t ws_size,
                              hipStream_t stream){
  const float* hidden = (const float*)d_in[0];
  const float* img    = (const float*)d_in[1];
  const float* cov    = (const float*)d_in[2];
  const float* W_h    = (const float*)d_in[3];
  const float* b_h    = (const float*)d_in[4];
  const float* W_img  = (const float*)d_in[5];
  const float* b_img  = (const float*)d_in[6];
  const float* W_cov  = (const float*)d_in[7];
  const float* v      = (const float*)d_in[8];

  char* ws = (char*)d_ws;
  unsigned short* WtH   = (unsigned short*)ws;               // 1 MB
  unsigned short* WtImg = (unsigned short*)(ws + (1u<<20));  // 1 MB
  float* hproj   = (float*)(ws + (2u<<20));                  // 4 MB
  float* scoresF = (float*)(ws + (6u<<20));                  // fallback scores
  unsigned short* imgb = (unsigned short*)(ws + (8u<<20));   // 196 MB bf16 copy

  float* outCtx   = (float*)d_out;
  float* outAlpha = outCtx + (size_t)B_*H_;

  const size_t needed = (8ull<<20) + (size_t)M_*H_*2;

  k_transpose<<<dim3(512, 2), 256, 0, stream>>>(W_h, W_img, WtH, WtImg);
  k_hproj<<<dim3(B_/128, A_/128), 256, 0, stream>>>(hidden, WtH, b_h, hproj);

  if (ws_size >= needed){
    k_fused<<<NBLK, 512, 0, stream>>>(img, imgb, WtImg, hproj, b_img, cov, W_cov, v,
                                      outCtx, outAlpha);
  } else {
    hipMemsetAsync(scoresF, 0, (size_t)M_*sizeof(float), stream);
    k_scores_f<<<dim3(M_/128, A_/128), 256, 0, stream>>>(img, WtImg, hproj, b_img, cov, W_cov, v, scoresF);
    k_ctx_f<<<B_, 256, 0, stream>>>(img, scoresF, outCtx, outAlpha);
  }
}